// Round 1
// 357.423 us; speedup vs baseline: 1.1365x; 1.1365x over previous
//
#include <hip/hip_runtime.h>

#define N_NODES 100000
#define N_EDGES 800000

typedef unsigned short u16;
typedef unsigned int u32;
typedef __attribute__((ext_vector_type(8))) short short8;
typedef __attribute__((ext_vector_type(4))) float floatx4;

__device__ __forceinline__ float bflo(u32 u) {
    union { u32 i; float f; } v; v.i = u << 16; return v.f;
}
__device__ __forceinline__ float bfhi(u32 u) {
    union { u32 i; float f; } v; v.i = u & 0xFFFF0000u; return v.f;
}
__device__ __forceinline__ u16 f2bf(float f) {
    union { float f; u32 i; } v; v.f = f;
    u32 r = (v.i + 0x7FFFu + ((v.i >> 16) & 1u)) >> 16;
    return (u16)r;
}
__device__ __forceinline__ float fast_tanh(float x) {
    float e = __expf(2.0f * x);
    return 1.0f - 2.0f * __builtin_amdgcn_rcpf(e + 1.0f);
}

// ---------------- degree + rank (rank makes the scatter atomic-free) ----------------

__global__ void k_deg(const int* __restrict__ src, const int* __restrict__ dst,
                      int* out_deg, int* in_deg, int* __restrict__ rank) {
    int e = blockIdx.x * 256 + threadIdx.x;
    if (e < N_EDGES) {
        atomicAdd(&out_deg[src[e]], 1);
        rank[e] = atomicAdd(&in_deg[dst[e]], 1);
    }
}

__global__ void k_scan1(const int* __restrict__ in_deg, int* blockSums) {
    __shared__ int red[256];
    int t = threadIdx.x;
    int base = blockIdx.x * 1024 + t * 4;
    int s = 0;
#pragma unroll
    for (int j = 0; j < 4; j++) { int idx = base + j; if (idx < N_NODES) s += in_deg[idx]; }
    red[t] = s; __syncthreads();
    for (int off = 128; off > 0; off >>= 1) {
        if (t < off) red[t] += red[t + off];
        __syncthreads();
    }
    if (t == 0) blockSums[blockIdx.x] = red[0];
}

__global__ void k_scan3(const int* __restrict__ in_deg, const int* __restrict__ out_deg,
                        const int* __restrict__ blockSums,
                        int* csr_start, float* out_scale, float* in_scale) {
    __shared__ int sc[256];
    __shared__ int boff;
    int t = threadIdx.x;
    if (t < 64) {
        int s = 0;
        for (int i = t; i < blockIdx.x; i += 64) s += blockSums[i];
#pragma unroll
        for (int o = 32; o > 0; o >>= 1) s += __shfl_down(s, o);
        if (t == 0) boff = s;
    }
    int base = blockIdx.x * 1024 + t * 4;
    int d[4]; int s = 0;
#pragma unroll
    for (int j = 0; j < 4; j++) { int idx = base + j; d[j] = (idx < N_NODES) ? in_deg[idx] : 0; s += d[j]; }
    sc[t] = s; __syncthreads();
    for (int off = 1; off < 256; off <<= 1) {
        int v = (t >= off) ? sc[t - off] : 0;
        __syncthreads();
        sc[t] += v;
        __syncthreads();
    }
    int excl = sc[t] - s;
    int run = boff + excl;
#pragma unroll
    for (int j = 0; j < 4; j++) {
        int idx = base + j;
        if (idx < N_NODES) {
            csr_start[idx] = run; run += d[j];
            int od = out_deg[idx]; if (od < 1) od = 1;
            out_scale[idx] = rsqrtf((float)od);
            int id = d[j]; if (id < 1) id = 1;
            in_scale[idx] = rsqrtf((float)id);
        }
    }
}

// ---------------- mid stage: atomic-free scatter + weight-frag prep ----------------
// frag layout [m][ot][ks][lane][j]: ot=o>>4, ks=k>>5, quad=(k>>3)&3, j=k&7, lane=(quad<<4)|(o&15)

#define NB_SCAT 3125
#define NB_PREPW 192
__global__ void k_mid(const int* __restrict__ src, const int* __restrict__ dst,
                      const int* __restrict__ attr, const int* __restrict__ rank,
                      const int* __restrict__ csr_start, int* __restrict__ csr_edge,
                      const float* __restrict__ w1, const float* __restrict__ w2,
                      const float* __restrict__ v, u16* __restrict__ wvfrag) {
    int b = blockIdx.x;
    if (b < NB_SCAT) {
        int e = b * 256 + threadIdx.x;
        if (e < N_EDGES) {
            int d = dst[e];
            int pos = csr_start[d] + rank[e];
            csr_edge[pos] = (src[e] << 5) | attr[e];
        }
    } else {
        int idx = (b - NB_SCAT) * 256 + threadIdx.x;   // 3*16384
        if (idx < 3 * 16384) {
            int m = idx >> 14, r = idx & 16383;
            int k = r >> 7, o = r & 127;
            float val = (m == 0) ? w1[k * 128 + o] : (m == 1) ? w2[k * 128 + o] : v[k * 128 + o];
            int ot = o >> 4, ks = k >> 5, quad = (k >> 3) & 3, j = k & 7;
            int lane = (quad << 4) | (o & 15);
            wvfrag[(((m * 8 + ot) * 4 + ks) * 64 + lane) * 8 + j] = f2bf(val);
        }
    }
}

// ---------------- fused node GEMMs (both m share the A operand) ----------------
// hrow layout (256 u16 per node): u16 idx 2o = h_sum(o), 2o+1 = h_prod(o)  -> one u32 per (node,o)
// A-frags converted from fp32 feat in-register (featb buffer eliminated).

__global__ __launch_bounds__(256) void k_gemm(const float* __restrict__ feat,
                                              const float* __restrict__ out_scale,
                                              const u16* __restrict__ wvfrag,
                                              const float* __restrict__ w2,
                                              u16* __restrict__ hrow) {
    __shared__ u16 ldsw[32768];  // 64 KB: m=0 (w1) then m=1 (w2)
    for (int i = threadIdx.x; i < 4096; i += 256)
        ((ulonglong2*)ldsw)[i] = ((const ulonglong2*)wvfrag)[i];
    __syncthreads();
    int wave = threadIdx.x >> 6, lane = threadIdx.x & 63;
    int quad = lane >> 4, l15 = lane & 15;
    const float* bias = w2 + 128 * 128;
    float bias_v[8];
#pragma unroll
    for (int ot = 0; ot < 8; ot++) bias_v[ot] = bias[ot * 16 + l15];
    const int NT = (N_NODES + 63) / 64;
    for (int tile = blockIdx.x; tile < NT; tile += gridDim.x) {
        int nb = tile * 64 + wave * 16;
        int anode = nb + l15; if (anode >= N_NODES) anode = N_NODES - 1;
        float s = out_scale[anode];
        short8 a[4];
#pragma unroll
        for (int ks = 0; ks < 4; ks++) {
            float4 f0 = *(const float4*)(feat + anode * 128 + ks * 32 + quad * 8);
            float4 f1 = *(const float4*)(feat + anode * 128 + ks * 32 + quad * 8 + 4);
            short8 av;
            av[0] = (short)f2bf(f0.x * s); av[1] = (short)f2bf(f0.y * s);
            av[2] = (short)f2bf(f0.z * s); av[3] = (short)f2bf(f0.w * s);
            av[4] = (short)f2bf(f1.x * s); av[5] = (short)f2bf(f1.y * s);
            av[6] = (short)f2bf(f1.z * s); av[7] = (short)f2bf(f1.w * s);
            a[ks] = av;
        }
#pragma unroll
        for (int ot = 0; ot < 8; ot++) {
            floatx4 accS = (floatx4){0.f, 0.f, 0.f, 0.f};
            floatx4 accP = (floatx4){0.f, 0.f, 0.f, 0.f};
#pragma unroll
            for (int ks = 0; ks < 4; ks++) {
                short8 b0 = *(const short8*)&ldsw[((ot * 4 + ks) * 64 + lane) * 8];
                short8 b1 = *(const short8*)&ldsw[16384 + ((ot * 4 + ks) * 64 + lane) * 8];
                accS = __builtin_amdgcn_mfma_f32_16x16x32_bf16(a[ks], b0, accS, 0, 0, 0);
                accP = __builtin_amdgcn_mfma_f32_16x16x32_bf16(a[ks], b1, accP, 0, 0, 0);
            }
            int o = ot * 16 + l15;
#pragma unroll
            for (int r = 0; r < 4; r++) {
                int node = nb + quad * 4 + r;
                if (node < N_NODES) {
                    u32 pv = (u32)f2bf(accS[r]) | ((u32)f2bf(fast_tanh(accP[r] + bias_v[ot])) << 16);
                    *(u32*)(hrow + node * 256 + o * 2) = pv;  // coalesced: 16 lanes -> 64 B line
                }
            }
        }
    }
}

// ---------------- edge stage: branch-free dual-stream main loop ----------------
// Keys are clamp-loaded (lane>=c reads key[c-1]) so ANY readlane idx 0..63 is a valid key:
// prefetches need no guards. Clean loop over min(c0,c1) (unconditional, unroll-2 so the
// compiler renames the pipeline regs and counts vmcnt precisely), then per-stream tails.
// hrow uint2 per lane: .x = {sum(2l) | prod(2l)<<16}, .y = {sum(2l+1) | prod(2l+1)<<16}

__global__ __launch_bounds__(256, 8) void k_edge(const int* __restrict__ csr_start, const int* __restrict__ in_deg,
                                                 const int* __restrict__ csr_edge,
                                                 const u16* __restrict__ hrow,
                                                 const float* __restrict__ bond_emb,
                                                 float* __restrict__ out_hs, u16* __restrict__ hp) {
    int wid = (blockIdx.x * 256 + threadIdx.x) >> 6;
    int lane = threadIdx.x & 63;
    int nwaves = (gridDim.x * 256) >> 6;
    const int NPAIR = N_NODES / 2;
    for (int pr = wid; pr < NPAIR; pr += nwaves) {
        int n0 = pr * 2, n1 = n0 + 1;
        int st0 = csr_start[n0];
        int2 dd = *(const int2*)(in_deg + n0);     // n0 even -> 8B aligned
        int d0 = dd.x, d1 = dd.y;
        int st1 = st0 + d0;                         // CSR prefix property
        float as0 = 0.f, as1 = 0.f, ap0 = 1.f, ap1 = 1.f;
        float bs0 = 0.f, bs1 = 0.f, bp0 = 1.f, bp1 = 1.f;
        for (int b = 0; (b < d0) || (b < d1); b += 64) {
            int c0 = d0 - b; c0 = c0 < 0 ? 0 : (c0 > 64 ? 64 : c0);
            int c1 = d1 - b; c1 = c1 < 0 ? 0 : (c1 > 64 ? 64 : c1);
            int pkv0 = 0, pkv1 = 0;
            if (c0 > 0) { int li = lane < c0 ? lane : c0 - 1; pkv0 = csr_edge[st0 + b + li]; }
            if (c1 > 0) { int li = lane < c1 ? lane : c1 - 1; pkv1 = csr_edge[st1 + b + li]; }
            uint2 hA0 = {0, 0}, hB0 = {0, 0}, hA1 = {0, 0}, hB1 = {0, 0};
            float2 eA0 = {0.f, 0.f}, eB0 = {0.f, 0.f}, eA1 = {0.f, 0.f}, eB1 = {0.f, 0.f};
            if (c0 > 0) {
                int pk = __builtin_amdgcn_readlane(pkv0, 0);
                hA0 = *(const uint2*)(hrow + (pk >> 5) * 256 + 4 * lane);
                eA0 = *(const float2*)(bond_emb + (pk & 31) * 128 + 2 * lane);
                pk = __builtin_amdgcn_readlane(pkv0, 1);
                hB0 = *(const uint2*)(hrow + (pk >> 5) * 256 + 4 * lane);
                eB0 = *(const float2*)(bond_emb + (pk & 31) * 128 + 2 * lane);
            }
            if (c1 > 0) {
                int pk = __builtin_amdgcn_readlane(pkv1, 0);
                hA1 = *(const uint2*)(hrow + (pk >> 5) * 256 + 4 * lane);
                eA1 = *(const float2*)(bond_emb + (pk & 31) * 128 + 2 * lane);
                pk = __builtin_amdgcn_readlane(pkv1, 1);
                hB1 = *(const uint2*)(hrow + (pk >> 5) * 256 + 4 * lane);
                eB1 = *(const float2*)(bond_emb + (pk & 31) * 128 + 2 * lane);
            }
            int cmin = c0 < c1 ? c0 : c1;
#pragma unroll 2
            for (int j = 0; j < cmin; j++) {
                int jn = j + 2; jn = jn > 63 ? 63 : jn;
                int pk = __builtin_amdgcn_readlane(pkv0, jn);
                uint2 hC0 = *(const uint2*)(hrow + (pk >> 5) * 256 + 4 * lane);
                float2 eC0 = *(const float2*)(bond_emb + (pk & 31) * 128 + 2 * lane);
                pk = __builtin_amdgcn_readlane(pkv1, jn);
                uint2 hC1 = *(const uint2*)(hrow + (pk >> 5) * 256 + 4 * lane);
                float2 eC1 = *(const float2*)(bond_emb + (pk & 31) * 128 + 2 * lane);
                as0 += bflo(hA0.x) * eA0.x; ap0 *= bfhi(hA0.x) * eA0.x;
                as1 += bflo(hA0.y) * eA0.y; ap1 *= bfhi(hA0.y) * eA0.y;
                bs0 += bflo(hA1.x) * eA1.x; bp0 *= bfhi(hA1.x) * eA1.x;
                bs1 += bflo(hA1.y) * eA1.y; bp1 *= bfhi(hA1.y) * eA1.y;
                hA0 = hB0; eA0 = eB0; hB0 = hC0; eB0 = eC0;
                hA1 = hB1; eA1 = eB1; hB1 = hC1; eB1 = eC1;
            }
            for (int t = cmin; t < c0; t++) {
                int jn = t + 2; jn = jn > 63 ? 63 : jn;
                int pk = __builtin_amdgcn_readlane(pkv0, jn);
                uint2 hC0 = *(const uint2*)(hrow + (pk >> 5) * 256 + 4 * lane);
                float2 eC0 = *(const float2*)(bond_emb + (pk & 31) * 128 + 2 * lane);
                as0 += bflo(hA0.x) * eA0.x; ap0 *= bfhi(hA0.x) * eA0.x;
                as1 += bflo(hA0.y) * eA0.y; ap1 *= bfhi(hA0.y) * eA0.y;
                hA0 = hB0; eA0 = eB0; hB0 = hC0; eB0 = eC0;
            }
            for (int t = cmin; t < c1; t++) {
                int jn = t + 2; jn = jn > 63 ? 63 : jn;
                int pk = __builtin_amdgcn_readlane(pkv1, jn);
                uint2 hC1 = *(const uint2*)(hrow + (pk >> 5) * 256 + 4 * lane);
                float2 eC1 = *(const float2*)(bond_emb + (pk & 31) * 128 + 2 * lane);
                bs0 += bflo(hA1.x) * eA1.x; bp0 *= bfhi(hA1.x) * eA1.x;
                bs1 += bflo(hA1.y) * eA1.y; bp1 *= bfhi(hA1.y) * eA1.y;
                hA1 = hB1; eA1 = eB1; hB1 = hC1; eB1 = eC1;
            }
        }
        float2 sv0; sv0.x = as0; sv0.y = as1;
        float2 sv1; sv1.x = bs0; sv1.y = bs1;
        *(float2*)(out_hs + n0 * 128 + 2 * lane) = sv0;
        *(float2*)(out_hs + n1 * 128 + 2 * lane) = sv1;
        *(u32*)(hp + n0 * 128 + 2 * lane) = ((u32)f2bf(ap1) << 16) | (u32)f2bf(ap0);
        *(u32*)(hp + n1 * 128 + 2 * lane) = ((u32)f2bf(bp1) << 16) | (u32)f2bf(bp0);
    }
}

// ---------------- final: out = (hs + hp@v) * in_scale ; hs lives in d_out ----------------

__global__ __launch_bounds__(256) void k_final(const u16* __restrict__ hp,
                                               const u16* __restrict__ vfrag,
                                               const float* __restrict__ in_scale,
                                               float* __restrict__ out) {
    __shared__ u16 ldsw[16384];  // 32 KB
    for (int i = threadIdx.x; i < 2048; i += 256)
        ((ulonglong2*)ldsw)[i] = ((const ulonglong2*)vfrag)[i];
    __syncthreads();
    int wave = threadIdx.x >> 6, lane = threadIdx.x & 63;
    int quad = lane >> 4, l15 = lane & 15;
    const int NT = (N_NODES + 63) / 64;
    for (int tile = blockIdx.x; tile < NT; tile += gridDim.x) {
        int nb = tile * 64 + wave * 16;
        int anode = nb + l15; if (anode >= N_NODES) anode = N_NODES - 1;
        short8 a[4];
#pragma unroll
        for (int ks = 0; ks < 4; ks++)
            a[ks] = *(const short8*)(hp + anode * 128 + ks * 32 + quad * 8);
#pragma unroll
        for (int ot = 0; ot < 8; ot++) {
            floatx4 acc = (floatx4){0.f, 0.f, 0.f, 0.f};
#pragma unroll
            for (int ks = 0; ks < 4; ks++) {
                short8 b = *(const short8*)&ldsw[((ot * 4 + ks) * 64 + lane) * 8];
                acc = __builtin_amdgcn_mfma_f32_16x16x32_bf16(a[ks], b, acc, 0, 0, 0);
            }
            int o = ot * 16 + l15;
#pragma unroll
            for (int r = 0; r < 4; r++) {
                int node = nb + quad * 4 + r;
                if (node < N_NODES) {
                    float scl = in_scale[node];
                    float hsv = out[node * 128 + o];          // hs, written by k_edge
                    out[node * 128 + o] = (acc[r] + hsv) * scl;
                }
            }
        }
    }
}

extern "C" void kernel_launch(void* const* d_in, const int* in_sizes, int n_in,
                              void* d_out, int out_size, void* d_ws, size_t ws_size,
                              hipStream_t stream) {
    const float* feat = (const float*)d_in[0];
    const int* src = (const int*)d_in[1];
    const int* dst = (const int*)d_in[2];
    const int* attr = (const int*)d_in[3];
    const float* w1 = (const float*)d_in[4];
    const float* w2 = (const float*)d_in[5];
    const float* v = (const float*)d_in[6];
    const float* bond = (const float*)d_in[7];
    float* out = (float*)d_out;

    char* ws = (char*)d_ws;
    size_t off = 0;
    auto alloc = [&](size_t bytes) -> char* {
        char* p = ws + off; off += (bytes + 255) & ~(size_t)255; return p;
    };
    int* deg2      = (int*)alloc((size_t)2 * N_NODES * 4);   // out_deg | in_deg, one memset
    int* out_deg   = deg2;
    int* in_deg    = deg2 + N_NODES;
    int* csr_start = (int*)alloc((size_t)N_NODES * 4);
    int* rank      = (int*)alloc((size_t)N_EDGES * 4);
    int* blockSums = (int*)alloc(1024 * 4);
    float* out_scale = (float*)alloc((size_t)N_NODES * 4);
    float* in_scale  = (float*)alloc((size_t)N_NODES * 4);
    int* csr_edge  = (int*)alloc((size_t)N_EDGES * 4);
    u16* wvfrag = (u16*)alloc((size_t)3 * 16384 * 2);         // w1|w2|v bf16 frags
    u16* hrow   = (u16*)alloc((size_t)N_NODES * 256 * 2);     // [sum|prod] per channel
    u16* hp     = (u16*)alloc((size_t)N_NODES * 128 * 2);

    (void)in_sizes; (void)n_in; (void)out_size; (void)ws_size;

    int nb = (N_NODES + 1023) / 1024;
    hipMemsetAsync(deg2, 0, (size_t)2 * N_NODES * 4, stream);
    k_deg<<<(N_EDGES + 255) / 256, 256, 0, stream>>>(src, dst, out_deg, in_deg, rank);
    k_scan1<<<nb, 256, 0, stream>>>(in_deg, blockSums);
    k_scan3<<<nb, 256, 0, stream>>>(in_deg, out_deg, blockSums, csr_start, out_scale, in_scale);
    k_mid<<<NB_SCAT + NB_PREPW, 256, 0, stream>>>(src, dst, attr, rank, csr_start, csr_edge,
                                                  w1, w2, v, wvfrag);
    k_gemm<<<512, 256, 0, stream>>>(feat, out_scale, wvfrag, w2, hrow);
    k_edge<<<2048, 256, 0, stream>>>(csr_start, in_deg, csr_edge, hrow, bond, out, hp);
    k_final<<<1280, 256, 0, stream>>>(hp, wvfrag + 2 * 16384, in_scale, out);
}